// Round 4
// baseline (164.058 us; speedup 1.0000x reference)
//
#include <hip/hip_runtime.h>
#include <cmath>

// GAT layer: N=4096 nodes, FIN=128, F=64 per head, H=8 heads.
// Pipeline:
//   k0: pack A (int32 dense) -> 64-bit masks (2 MB); 2 extra blocks
//       transpose W -> f16 Wt16[h][f][k] (128 KB) for direct B-frag loads
//   k1: feats = X @ W[h] via f16 MFMA, NO LDS: A-frags direct from X (fp32,
//       cvt), B-frags direct from Wt16; factored exps es/esn/et/etn (f16);
//       feats stored f16 in MFMA-B-swizzled order
//   k2: P[n,m] = mask * max(es_n*et_m, esn_n*etn_m)  (= exp(LReLU(s+t)-4))
//       packed f16; conflict-free 16-entry nibble LUT; denom via
//       v_dot2_f32_f16 (2 alternating accumulators); PV via
//       v_mfma_f32_16x16x32_f16; 4-phase epilogue keeps LDS at 36 KB
//       -> 3 blocks/CU.

#define NN 4096
#define FIN 128
#define FF 64
#define HH 8

typedef _Float16 h2 __attribute__((ext_vector_type(2)));
typedef _Float16 h4 __attribute__((ext_vector_type(4)));
typedef _Float16 h8 __attribute__((ext_vector_type(8)));
typedef float f32x2 __attribute__((ext_vector_type(2)));
typedef float f32x4 __attribute__((ext_vector_type(4)));

union H8 {
  h8 v;
  h2 p[4];
};
union H4 {
  h4 v;
  h2 p[2];
};

static __device__ __forceinline__ float dot2acc(h2 a, float c) {
#if __has_builtin(__builtin_amdgcn_fdot2)
  return __builtin_amdgcn_fdot2(a, (h2){(_Float16)1.f, (_Float16)1.f}, c,
                                false);
#else
  return c + (float)a[0] + (float)a[1];
#endif
}

// ---------------------------------------------------------------- kernel 0
// blocks [0,NN): pack one A-row into 64 u64 masks (4 indep loads in flight).
// blocks [NN,NN+2): transpose 4 heads of W each -> f16 Wt16[h][f][k].
__global__ __launch_bounds__(256) void pack_kernel(
    const int* __restrict__ A, const float* __restrict__ W,
    unsigned long long* __restrict__ bits, _Float16* __restrict__ Wt16) {
  const int b = blockIdx.x;
  const int tid = threadIdx.x;
  if (b < NN) {
    const int wave = tid >> 6, lane = tid & 63;
    const int* ar = A + (size_t)b * NN;
#pragma unroll
    for (int g = 0; g < 4; ++g) {
      const int w0 = wave * 16 + g * 4;
      int v0 = ar[(w0 + 0) * 64 + lane];
      int v1 = ar[(w0 + 1) * 64 + lane];
      int v2 = ar[(w0 + 2) * 64 + lane];
      int v3 = ar[(w0 + 3) * 64 + lane];
      unsigned long long m0 = __ballot(v0 != 0);
      unsigned long long m1 = __ballot(v1 != 0);
      unsigned long long m2 = __ballot(v2 != 0);
      unsigned long long m3 = __ballot(v3 != 0);
      if (lane == 0) {
        bits[(b << 6) + w0 + 0] = m0;
        bits[(b << 6) + w0 + 1] = m1;
        bits[(b << 6) + w0 + 2] = m2;
        bits[(b << 6) + w0 + 3] = m3;
      }
    }
  } else {
    const int h0 = (b - NN) * 4;
    for (int h = h0; h < h0 + 4; ++h) {
      for (int idx = tid; idx < FIN * (FF / 4); idx += 256) {
        int k = idx >> 4, f4 = (idx & 15) << 2;
        f32x4 w = *(const f32x4*)(W + ((size_t)(h * FIN + k)) * FF + f4);
#pragma unroll
        for (int j = 0; j < 4; ++j)
          Wt16[((size_t)(h * FF + f4 + j)) * FIN + k] = (_Float16)w[j];
      }
    }
  }
}

// ---------------------------------------------------------------- kernel 1
// grid (64 rowblocks, 8 heads), 256 thr = 4 waves x 16 rows. No LDS tiles.
// A-frag: X[r0+l16][kt*32+quad*8 .. +7] fp32->f16; B-frag: Wt16 direct.
__global__ __launch_bounds__(256) void feats_kernel(
    const float* __restrict__ X, const _Float16* __restrict__ Wt16,
    const float* __restrict__ a_self, const float* __restrict__ a_neigh,
    _Float16* __restrict__ feats_sw, _Float16* __restrict__ es_h,
    _Float16* __restrict__ esn_h, _Float16* __restrict__ et_h,
    _Float16* __restrict__ etn_h) {
  const int h = blockIdx.y;
  const int tid = threadIdx.x, wave = tid >> 6, lane = tid & 63;
  const int l16 = lane & 15, quad = lane >> 4;
  const int r0 = blockIdx.x * 64 + wave * 16;

  f32x4 acc[4];
#pragma unroll
  for (int nb = 0; nb < 4; ++nb) acc[nb] = (f32x4){0.f, 0.f, 0.f, 0.f};

  const float* xr = X + (size_t)(r0 + l16) * FIN;
  const _Float16* wb = Wt16 + (size_t)h * FF * FIN;
#pragma unroll
  for (int kt = 0; kt < 4; ++kt) {
    const int kof = kt * 32 + quad * 8;
    f32x4 x0 = *(const f32x4*)(xr + kof);
    f32x4 x1 = *(const f32x4*)(xr + kof + 4);
    h8 Af = {(_Float16)x0[0], (_Float16)x0[1], (_Float16)x0[2],
             (_Float16)x0[3], (_Float16)x1[0], (_Float16)x1[1],
             (_Float16)x1[2], (_Float16)x1[3]};
#pragma unroll
    for (int nb = 0; nb < 4; ++nb) {
      h8 Bf = *(const h8*)(wb + (size_t)(nb * 16 + l16) * FIN + kof);
      acc[nb] = __builtin_amdgcn_mfma_f32_16x16x32_f16(Af, Bf, acc[nb], 0, 0, 0);
    }
  }

  // s_self/s_neigh dots (fp32) -> factored exponentials (f16)
  float as[4], an[4];
#pragma unroll
  for (int nb = 0; nb < 4; ++nb) {
    as[nb] = a_self[h * FF + nb * 16 + l16];
    an[nb] = a_neigh[h * FF + nb * 16 + l16];
  }
#pragma unroll
  for (int r = 0; r < 4; ++r) {
    float ps = acc[0][r] * as[0] + acc[1][r] * as[1] + acc[2][r] * as[2] +
               acc[3][r] * as[3];
    float pn = acc[0][r] * an[0] + acc[1][r] * an[1] + acc[2][r] * an[2] +
               acc[3][r] * an[3];
#pragma unroll
    for (int m = 1; m <= 8; m <<= 1) {
      ps += __shfl_xor(ps, m, 64);
      pn += __shfl_xor(pn, m, 64);
    }
    if (l16 == 0) {
      int node = h * NN + r0 + quad * 4 + r;
      es_h[node] = (_Float16)__expf(ps - 2.0f);
      esn_h[node] = (_Float16)__expf(0.2f * ps - 2.0f);
      et_h[node] = (_Float16)__expf(pn - 2.0f);
      etn_h[node] = (_Float16)__expf(0.2f * pn - 2.0f);
    }
  }

  // swizzled f16 store (MFMA B-fragment order). node = r0 + quad*4 + r.
  const int kb = r0 >> 5;
  const int quadA = ((r0 >> 4) & 1) * 2 + (quad >> 1);
  const int jbase = (quad & 1) << 2;
#pragma unroll
  for (int nb = 0; nb < 4; ++nb) {
    h4 v = {(_Float16)acc[nb][0], (_Float16)acc[nb][1], (_Float16)acc[nb][2],
            (_Float16)acc[nb][3]};
    size_t off = ((size_t)((h * 128 + kb) * 4 + nb) << 9) +
                 ((quadA * 16 + l16) << 3) + jbase;
    *(h4*)(feats_sw + off) = v;
  }
}

// ---------------------------------------------------------------- kernel 2
// grid 512 = rb*8 + h (one head per XCD -> 512 KB feats L2-resident).
// 64 rows/block, 512 threads = 8 waves splitting the 64 column tiles.
// 4-phase epilogue keeps LDS at ~36 KB -> 3 blocks/CU.
__global__ __launch_bounds__(512, 4) void attn_kernel(
    const unsigned long long* __restrict__ Abits,
    const _Float16* __restrict__ feats_sw, const _Float16* __restrict__ es_h,
    const _Float16* __restrict__ esn_h, const _Float16* __restrict__ et_h,
    const _Float16* __restrict__ etn_h, const float* __restrict__ bias,
    float* __restrict__ out) {
  const int bid = blockIdx.x;
  const int h = bid & 7, n0 = (bid >> 3) << 6;
  const int tid = threadIdx.x, wave = tid >> 6, lane = tid & 63;
  const int l16 = lane & 15, quad = lane >> 4;

  __shared__ h4 lut16[16];           // 16 x 8B = exactly 32 banks
  __shared__ float accL[8][16][66];  // 33.8 KB (phase-sized)
  __shared__ float denL[8][64];
  if (tid < 16) {
    h4 m;
#pragma unroll
    for (int j = 0; j < 4; ++j) m[j] = (_Float16)((tid >> j) & 1);
    lut16[tid] = m;
  }
  __syncthreads();

  h2 esp[4], esnp[4];
#pragma unroll
  for (int rg = 0; rg < 4; ++rg) {
    _Float16 e = es_h[h * NN + n0 + rg * 16 + l16];
    _Float16 en = esn_h[h * NN + n0 + rg * 16 + l16];
    esp[rg] = (h2){e, e};
    esnp[rg] = (h2){en, en};
  }

  f32x4 acc[4][4];
  float dsA[4] = {0.f, 0.f, 0.f, 0.f}, dsB[4] = {0.f, 0.f, 0.f, 0.f};
#pragma unroll
  for (int rg = 0; rg < 4; ++rg)
#pragma unroll
    for (int nb = 0; nb < 4; ++nb) acc[rg][nb] = (f32x4){0.f, 0.f, 0.f, 0.f};

  const uint2* ab = (const uint2*)Abits;
  const int rowbase = n0 + l16;
  const _Float16* etp = et_h + h * NN + (quad << 3);
  const _Float16* etnp = etn_h + h * NN + (quad << 3);
  const _Float16* fb = feats_sw + ((size_t)h << 18) + (lane << 3);

  for (int ct = wave; ct < 64; ct += 8) {
    uint2 bits[4];
#pragma unroll
    for (int rg = 0; rg < 4; ++rg)
      bits[rg] = ab[((rowbase + rg * 16) << 6) + ct];
    const _Float16* fbt = fb + (ct << 12);
#pragma unroll
    for (int kf = 0; kf < 2; ++kf) {
      H8 ET, ETN;
      ET.v = *(const h8*)(etp + (ct << 6) + kf * 32);
      ETN.v = *(const h8*)(etnp + (ct << 6) + kf * 32);
      const _Float16* fk = fbt + (kf << 11);
      h8 B0 = *(const h8*)(fk);
      h8 B1 = *(const h8*)(fk + 512);
      h8 B2 = *(const h8*)(fk + 1024);
      h8 B3 = *(const h8*)(fk + 1536);
#pragma unroll
      for (int rg = 0; rg < 4; ++rg) {
        unsigned word = kf ? bits[rg].y : bits[rg].x;
        unsigned byt = (word >> (quad << 3)) & 0xFFu;
        H4 mlo, mhi;
        mlo.v = lut16[byt & 15u];
        mhi.v = lut16[byt >> 4];
        H8 P;
#pragma unroll
        for (int p = 0; p < 4; ++p) {
          h2 a = esp[rg] * ET.p[p];
          h2 b = esnp[rg] * ETN.p[p];
          h2 r = __builtin_elementwise_max(a, b);
          h2 pm = r * (p < 2 ? mlo.p[p] : mhi.p[p - 2]);
          P.p[p] = pm;
          if (p & 1)
            dsB[rg] = dot2acc(pm, dsB[rg]);
          else
            dsA[rg] = dot2acc(pm, dsA[rg]);
        }
        acc[rg][0] =
            __builtin_amdgcn_mfma_f32_16x16x32_f16(P.v, B0, acc[rg][0], 0, 0, 0);
        acc[rg][1] =
            __builtin_amdgcn_mfma_f32_16x16x32_f16(P.v, B1, acc[rg][1], 0, 0, 0);
        acc[rg][2] =
            __builtin_amdgcn_mfma_f32_16x16x32_f16(P.v, B2, acc[rg][2], 0, 0, 0);
        acc[rg][3] =
            __builtin_amdgcn_mfma_f32_16x16x32_f16(P.v, B3, acc[rg][3], 0, 0, 0);
      }
    }
  }

  // denominator partials per wave
#pragma unroll
  for (int rg = 0; rg < 4; ++rg) {
    float d = dsA[rg] + dsB[rg];
    d += __shfl_xor(d, 16, 64);
    d += __shfl_xor(d, 32, 64);
    if (quad == 0) denL[wave][rg * 16 + l16] = d;
  }

  // 4-phase epilogue: 16 rows per phase, 8-way cross-wave reduce
  const int erow = tid >> 5, ec0 = (tid & 31) << 1;
#pragma unroll
  for (int ph = 0; ph < 4; ++ph) {
    __syncthreads();
#pragma unroll
    for (int nb = 0; nb < 4; ++nb)
#pragma unroll
      for (int r = 0; r < 4; ++r)
        accL[wave][quad * 4 + r][nb * 16 + l16] = acc[ph][nb][r];
    __syncthreads();
    const int grow = ph * 16 + erow;
    float dn = 0.f;
#pragma unroll
    for (int w = 0; w < 8; ++w) dn += denL[w][grow];
    float inv = 1.0f / dn;  // self loop -> dn > 0
    f32x2 v = (f32x2){0.f, 0.f};
#pragma unroll
    for (int w = 0; w < 8; ++w) v += *(const f32x2*)&accL[w][erow][ec0];
    const f32x2 bv = *(const f32x2*)(bias + h * FF + ec0);
#pragma unroll
    for (int i = 0; i < 2; ++i) {
      float x = v[i] * inv + bv[i];
      v[i] = x > 0.f ? x : (__expf(x) - 1.0f);
    }
    *(f32x2*)(out + (size_t)(n0 + grow) * (HH * FF) + h * FF + ec0) = v;
  }
}

// ---------------------------------------------------------------- launch
extern "C" void kernel_launch(void* const* d_in, const int* in_sizes, int n_in,
                              void* d_out, int out_size, void* d_ws,
                              size_t ws_size, hipStream_t stream) {
  const float* X = (const float*)d_in[0];
  const int* A = (const int*)d_in[1];
  const float* W = (const float*)d_in[2];
  const float* b = (const float*)d_in[3];
  const float* a_self = (const float*)d_in[4];
  const float* a_neigh = (const float*)d_in[5];
  float* out = (float*)d_out;

  char* ws = (char*)d_ws;
  unsigned long long* Abits = (unsigned long long*)ws;        // 2 MB
  _Float16* feats_sw = (_Float16*)(ws + (2u << 20));          // 4 MB
  _Float16* es_h = (_Float16*)(ws + (6u << 20));              // 64 KB each
  _Float16* esn_h = (_Float16*)(ws + (6u << 20) + (64u << 10));
  _Float16* et_h = (_Float16*)(ws + (6u << 20) + (128u << 10));
  _Float16* etn_h = (_Float16*)(ws + (6u << 20) + (192u << 10));
  _Float16* Wt16 = (_Float16*)(ws + (6u << 20) + (256u << 10));  // 128 KB

  pack_kernel<<<NN + 2, 256, 0, stream>>>(A, W, Abits, Wt16);
  feats_kernel<<<dim3(64, 8), 256, 0, stream>>>(X, Wt16, a_self, a_neigh,
                                                feats_sw, es_h, esn_h, et_h,
                                                etn_h);
  attn_kernel<<<512, 512, 0, stream>>>(Abits, feats_sw, es_h, esn_h, et_h,
                                       etn_h, b, out);
}

// Round 5
// 145.449 us; speedup vs baseline: 1.1279x; 1.1279x over previous
//
#include <hip/hip_runtime.h>
#include <cmath>

// GAT layer: N=4096 nodes, FIN=128, F=64 per head, H=8 heads.
// Pipeline:
//   k0: pack A (int32) -> 64-bit masks via dwordx4 loads + per-wave LDS
//       transpose + ballot (natural bit order); 2 extra blocks swizzle W
//       into MFMA B-frag order (Wsw); 64 extra blocks swizzle X (fp32->f16)
//       into MFMA A-frag order (Xsw)
//   k1: feats = X @ W[h] via f16 MFMA; ALL loads are lane*16B coalesced
//       fragment streams (no LDS); factored exps es/esn/et/etn (f16);
//       feats stored f16 in MFMA-B-swizzled order (natural node order)
//   k2: P[n,m] = mask * max(es_n*et_m, esn_n*etn_m)  (= exp(LReLU(s+t)-4))
//       packed f16; conflict-free 16-entry nibble LUT; denom via
//       v_dot2_f32_f16; PV via v_mfma_f32_16x16x32_f16; 4-phase epilogue.

#define NN 4096
#define FIN 128
#define FF 64
#define HH 8

typedef _Float16 h2 __attribute__((ext_vector_type(2)));
typedef _Float16 h4 __attribute__((ext_vector_type(4)));
typedef _Float16 h8 __attribute__((ext_vector_type(8)));
typedef float f32x2 __attribute__((ext_vector_type(2)));
typedef float f32x4 __attribute__((ext_vector_type(4)));

union H8 {
  h8 v;
  h2 p[4];
};
union H4 {
  h4 v;
  h2 p[2];
};

static __device__ __forceinline__ float dot2acc(h2 a, float c) {
#if __has_builtin(__builtin_amdgcn_fdot2)
  return __builtin_amdgcn_fdot2(a, (h2){(_Float16)1.f, (_Float16)1.f}, c,
                                false);
#else
  return c + (float)a[0] + (float)a[1];
#endif
}

// ---------------------------------------------------------------- kernel 0
// blocks [0,NN): pack one A-row. Lane loads int4 (coalesced 1KB/wave),
// per-wave LDS transpose restores col-per-lane order, 4 ballots per group.
// blocks [NN,NN+2): W -> f16 MFMA-B-frag order (4 heads each).
// blocks [NN+2,NN+66): X -> f16 MFMA-A-frag order (4 row-tiles each).
__global__ __launch_bounds__(256) void pack_kernel(
    const int* __restrict__ A, const float* __restrict__ W,
    const float* __restrict__ X, unsigned long long* __restrict__ bits,
    _Float16* __restrict__ Wsw, _Float16* __restrict__ Xsw) {
  const int b = blockIdx.x;
  const int tid = threadIdx.x;
  const int wave = tid >> 6, lane = tid & 63;
  if (b < NN) {
    __shared__ int ldsT[4][4][256];  // [wave][iter][col-within-group]
    const int* ar = A + (size_t)b * NN;
    int4 v[4];
#pragma unroll
    for (int it = 0; it < 4; ++it) {
      const int g = wave * 4 + it;  // 256-col group
      v[it] = *(const int4*)(ar + g * 256 + lane * 4);
    }
#pragma unroll
    for (int it = 0; it < 4; ++it) *(int4*)&ldsT[wave][it][lane * 4] = v[it];
    unsigned long long* br = bits + ((size_t)b << 6);
#pragma unroll
    for (int it = 0; it < 4; ++it) {
      const int g = wave * 4 + it;
      int w0 = ldsT[wave][it][0 * 64 + lane];
      int w1 = ldsT[wave][it][1 * 64 + lane];
      int w2 = ldsT[wave][it][2 * 64 + lane];
      int w3 = ldsT[wave][it][3 * 64 + lane];
      unsigned long long m0 = __ballot(w0 != 0);
      unsigned long long m1 = __ballot(w1 != 0);
      unsigned long long m2 = __ballot(w2 != 0);
      unsigned long long m3 = __ballot(w3 != 0);
      if (lane == 0) {
        ulonglong2 p0 = {m0, m1}, p1 = {m2, m3};
        *(ulonglong2*)(br + g * 4 + 0) = p0;
        *(ulonglong2*)(br + g * 4 + 2) = p1;
      }
    }
  } else if (b < NN + 2) {
    const int h0 = (b - NN) * 4;
    for (int h = h0; h < h0 + 4; ++h) {
      for (int c = tid; c < 1024; c += 256) {  // (kt, nb, lane)
        int ln = c & 63, nb = (c >> 6) & 3, kt = c >> 8;
        int f = nb * 16 + (ln & 15);
        int k0 = kt * 32 + (ln >> 4) * 8;
        h8 v;
#pragma unroll
        for (int j = 0; j < 8; ++j)
          v[j] = (_Float16)W[((size_t)(h * FIN) + k0 + j) * FF + f];
        *(h8*)(Wsw + ((size_t)(((h * 4 + kt) * 4 + nb) * 64 + ln)) * 8) = v;
      }
    }
  } else {
    const int tile = (b - NN - 2) * 4 + wave;  // 16-row tile, 0..255
    const int l16 = lane & 15, quad = lane >> 4;
    const float* xr = X + (size_t)(tile * 16 + l16) * FIN;
#pragma unroll
    for (int kt = 0; kt < 4; ++kt) {
      int k0 = kt * 32 + quad * 8;
      f32x4 x0 = *(const f32x4*)(xr + k0);
      f32x4 x1 = *(const f32x4*)(xr + k0 + 4);
      h8 v = {(_Float16)x0[0], (_Float16)x0[1], (_Float16)x0[2],
              (_Float16)x0[3], (_Float16)x1[0], (_Float16)x1[1],
              (_Float16)x1[2], (_Float16)x1[3]};
      *(h8*)(Xsw + ((size_t)((tile * 4 + kt) * 64 + lane)) * 8) = v;
    }
  }
}

// ---------------------------------------------------------------- kernel 1
// grid (64 rowblocks, 8 heads), 256 thr = 4 waves x 16 rows. No LDS.
// All fragment loads are lane*16B coalesced (Xsw / Wsw pre-swizzled).
__global__ __launch_bounds__(256) void feats_kernel(
    const _Float16* __restrict__ Xsw, const _Float16* __restrict__ Wsw,
    const float* __restrict__ a_self, const float* __restrict__ a_neigh,
    _Float16* __restrict__ feats_sw, _Float16* __restrict__ es_h,
    _Float16* __restrict__ esn_h, _Float16* __restrict__ et_h,
    _Float16* __restrict__ etn_h) {
  const int h = blockIdx.y;
  const int tid = threadIdx.x, wave = tid >> 6, lane = tid & 63;
  const int l16 = lane & 15, quad = lane >> 4;
  const int rt = blockIdx.x * 4 + wave;  // 16-row tile
  const int r0 = rt * 16;

  f32x4 acc[4];
#pragma unroll
  for (int nb = 0; nb < 4; ++nb) acc[nb] = (f32x4){0.f, 0.f, 0.f, 0.f};

  const _Float16* xp = Xsw + ((size_t)(rt * 4) * 64 + lane) * 8;
  const _Float16* wp = Wsw + ((size_t)(h * 16) * 64 + lane) * 8;
  h8 Af[4];
#pragma unroll
  for (int kt = 0; kt < 4; ++kt) Af[kt] = *(const h8*)(xp + kt * 512);
#pragma unroll
  for (int kt = 0; kt < 4; ++kt)
#pragma unroll
    for (int nb = 0; nb < 4; ++nb) {
      h8 Bf = *(const h8*)(wp + (kt * 4 + nb) * 512);
      acc[nb] = __builtin_amdgcn_mfma_f32_16x16x32_f16(Af[kt], Bf, acc[nb], 0, 0, 0);
    }

  // s_self/s_neigh dots (fp32) -> factored exponentials (f16)
  float as[4], an[4];
#pragma unroll
  for (int nb = 0; nb < 4; ++nb) {
    as[nb] = a_self[h * FF + nb * 16 + l16];
    an[nb] = a_neigh[h * FF + nb * 16 + l16];
  }
#pragma unroll
  for (int r = 0; r < 4; ++r) {
    float ps = acc[0][r] * as[0] + acc[1][r] * as[1] + acc[2][r] * as[2] +
               acc[3][r] * as[3];
    float pn = acc[0][r] * an[0] + acc[1][r] * an[1] + acc[2][r] * an[2] +
               acc[3][r] * an[3];
#pragma unroll
    for (int m = 1; m <= 8; m <<= 1) {
      ps += __shfl_xor(ps, m, 64);
      pn += __shfl_xor(pn, m, 64);
    }
    if (l16 == 0) {
      int node = h * NN + r0 + quad * 4 + r;
      es_h[node] = (_Float16)__expf(ps - 2.0f);
      esn_h[node] = (_Float16)__expf(0.2f * ps - 2.0f);
      et_h[node] = (_Float16)__expf(pn - 2.0f);
      etn_h[node] = (_Float16)__expf(0.2f * pn - 2.0f);
    }
  }

  // swizzled f16 store (MFMA B-fragment order). node = r0 + quad*4 + r.
  const int kb = r0 >> 5;
  const int quadA = ((r0 >> 4) & 1) * 2 + (quad >> 1);
  const int jbase = (quad & 1) << 2;
#pragma unroll
  for (int nb = 0; nb < 4; ++nb) {
    h4 v = {(_Float16)acc[nb][0], (_Float16)acc[nb][1], (_Float16)acc[nb][2],
            (_Float16)acc[nb][3]};
    size_t off = ((size_t)((h * 128 + kb) * 4 + nb) << 9) +
                 ((quadA * 16 + l16) << 3) + jbase;
    *(h4*)(feats_sw + off) = v;
  }
}

// ---------------------------------------------------------------- kernel 2
// grid 512 = rb*8 + h (one head per XCD -> 512 KB feats L2-resident).
// 64 rows/block, 512 threads = 8 waves splitting the 64 column tiles.
// 4-phase epilogue keeps LDS at ~36 KB.
__global__ __launch_bounds__(512, 4) void attn_kernel(
    const unsigned long long* __restrict__ Abits,
    const _Float16* __restrict__ feats_sw, const _Float16* __restrict__ es_h,
    const _Float16* __restrict__ esn_h, const _Float16* __restrict__ et_h,
    const _Float16* __restrict__ etn_h, const float* __restrict__ bias,
    float* __restrict__ out) {
  const int bid = blockIdx.x;
  const int h = bid & 7, n0 = (bid >> 3) << 6;
  const int tid = threadIdx.x, wave = tid >> 6, lane = tid & 63;
  const int l16 = lane & 15, quad = lane >> 4;

  __shared__ h4 lut16[16];           // 16 x 8B = exactly 32 banks
  __shared__ float accL[8][16][66];  // 33.8 KB (phase-sized)
  __shared__ float denL[8][64];
  if (tid < 16) {
    h4 m;
#pragma unroll
    for (int j = 0; j < 4; ++j) m[j] = (_Float16)((tid >> j) & 1);
    lut16[tid] = m;
  }
  __syncthreads();

  h2 esp[4], esnp[4];
#pragma unroll
  for (int rg = 0; rg < 4; ++rg) {
    _Float16 e = es_h[h * NN + n0 + rg * 16 + l16];
    _Float16 en = esn_h[h * NN + n0 + rg * 16 + l16];
    esp[rg] = (h2){e, e};
    esnp[rg] = (h2){en, en};
  }

  f32x4 acc[4][4];
  float dsA[4] = {0.f, 0.f, 0.f, 0.f}, dsB[4] = {0.f, 0.f, 0.f, 0.f};
#pragma unroll
  for (int rg = 0; rg < 4; ++rg)
#pragma unroll
    for (int nb = 0; nb < 4; ++nb) acc[rg][nb] = (f32x4){0.f, 0.f, 0.f, 0.f};

  const uint2* ab = (const uint2*)Abits;
  const int rowbase = n0 + l16;
  const _Float16* etp = et_h + h * NN + (quad << 3);
  const _Float16* etnp = etn_h + h * NN + (quad << 3);
  const _Float16* fb = feats_sw + ((size_t)h << 18) + (lane << 3);

  for (int ct = wave; ct < 64; ct += 8) {
    uint2 bits[4];
#pragma unroll
    for (int rg = 0; rg < 4; ++rg)
      bits[rg] = ab[((rowbase + rg * 16) << 6) + ct];
    const _Float16* fbt = fb + (ct << 12);
#pragma unroll
    for (int kf = 0; kf < 2; ++kf) {
      H8 ET, ETN;
      ET.v = *(const h8*)(etp + (ct << 6) + kf * 32);
      ETN.v = *(const h8*)(etnp + (ct << 6) + kf * 32);
      const _Float16* fk = fbt + (kf << 11);
      h8 B0 = *(const h8*)(fk);
      h8 B1 = *(const h8*)(fk + 512);
      h8 B2 = *(const h8*)(fk + 1024);
      h8 B3 = *(const h8*)(fk + 1536);
#pragma unroll
      for (int rg = 0; rg < 4; ++rg) {
        unsigned word = kf ? bits[rg].y : bits[rg].x;
        unsigned byt = (word >> (quad << 3)) & 0xFFu;
        H4 mlo, mhi;
        mlo.v = lut16[byt & 15u];
        mhi.v = lut16[byt >> 4];
        H8 P;
#pragma unroll
        for (int p = 0; p < 4; ++p) {
          h2 a = esp[rg] * ET.p[p];
          h2 b = esnp[rg] * ETN.p[p];
          h2 r = __builtin_elementwise_max(a, b);
          h2 pm = r * (p < 2 ? mlo.p[p] : mhi.p[p - 2]);
          P.p[p] = pm;
          if (p & 1)
            dsB[rg] = dot2acc(pm, dsB[rg]);
          else
            dsA[rg] = dot2acc(pm, dsA[rg]);
        }
        acc[rg][0] =
            __builtin_amdgcn_mfma_f32_16x16x32_f16(P.v, B0, acc[rg][0], 0, 0, 0);
        acc[rg][1] =
            __builtin_amdgcn_mfma_f32_16x16x32_f16(P.v, B1, acc[rg][1], 0, 0, 0);
        acc[rg][2] =
            __builtin_amdgcn_mfma_f32_16x16x32_f16(P.v, B2, acc[rg][2], 0, 0, 0);
        acc[rg][3] =
            __builtin_amdgcn_mfma_f32_16x16x32_f16(P.v, B3, acc[rg][3], 0, 0, 0);
      }
    }
  }

  // denominator partials per wave
#pragma unroll
  for (int rg = 0; rg < 4; ++rg) {
    float d = dsA[rg] + dsB[rg];
    d += __shfl_xor(d, 16, 64);
    d += __shfl_xor(d, 32, 64);
    if (quad == 0) denL[wave][rg * 16 + l16] = d;
  }

  // 4-phase epilogue: 16 rows per phase, 8-way cross-wave reduce
  const int erow = tid >> 5, ec0 = (tid & 31) << 1;
#pragma unroll
  for (int ph = 0; ph < 4; ++ph) {
    __syncthreads();
#pragma unroll
    for (int nb = 0; nb < 4; ++nb)
#pragma unroll
      for (int r = 0; r < 4; ++r)
        accL[wave][quad * 4 + r][nb * 16 + l16] = acc[ph][nb][r];
    __syncthreads();
    const int grow = ph * 16 + erow;
    float dn = 0.f;
#pragma unroll
    for (int w = 0; w < 8; ++w) dn += denL[w][grow];
    float inv = 1.0f / dn;  // self loop -> dn > 0
    f32x2 v = (f32x2){0.f, 0.f};
#pragma unroll
    for (int w = 0; w < 8; ++w) v += *(const f32x2*)&accL[w][erow][ec0];
    const f32x2 bv = *(const f32x2*)(bias + h * FF + ec0);
#pragma unroll
    for (int i = 0; i < 2; ++i) {
      float x = v[i] * inv + bv[i];
      v[i] = x > 0.f ? x : (__expf(x) - 1.0f);
    }
    *(f32x2*)(out + (size_t)(n0 + grow) * (HH * FF) + h * FF + ec0) = v;
  }
}

// ---------------------------------------------------------------- launch
extern "C" void kernel_launch(void* const* d_in, const int* in_sizes, int n_in,
                              void* d_out, int out_size, void* d_ws,
                              size_t ws_size, hipStream_t stream) {
  const float* X = (const float*)d_in[0];
  const int* A = (const int*)d_in[1];
  const float* W = (const float*)d_in[2];
  const float* b = (const float*)d_in[3];
  const float* a_self = (const float*)d_in[4];
  const float* a_neigh = (const float*)d_in[5];
  float* out = (float*)d_out;

  char* ws = (char*)d_ws;
  unsigned long long* Abits = (unsigned long long*)ws;        // 2 MB
  _Float16* feats_sw = (_Float16*)(ws + (2u << 20));          // 4 MB
  _Float16* es_h = (_Float16*)(ws + (6u << 20));              // 64 KB each
  _Float16* esn_h = (_Float16*)(ws + (6u << 20) + (64u << 10));
  _Float16* et_h = (_Float16*)(ws + (6u << 20) + (128u << 10));
  _Float16* etn_h = (_Float16*)(ws + (6u << 20) + (192u << 10));
  _Float16* Wsw = (_Float16*)(ws + (6u << 20) + (256u << 10));   // 128 KB
  _Float16* Xsw = (_Float16*)(ws + (6u << 20) + (384u << 10));   // 1 MB

  pack_kernel<<<NN + 66, 256, 0, stream>>>(A, W, X, Abits, Wsw, Xsw);
  feats_kernel<<<dim3(64, 8), 256, 0, stream>>>(Xsw, Wsw, a_self, a_neigh,
                                                feats_sw, es_h, esn_h, et_h,
                                                etn_h);
  attn_kernel<<<512, 512, 0, stream>>>(Abits, feats_sw, es_h, esn_h, et_h,
                                       etn_h, b, out);
}